// Round 14
// baseline (304.330 us; speedup 1.0000x reference)
//
#include <hip/hip_runtime.h>
#include <hip/hip_fp16.h>

// Problem constants (B,S,D fixed by the reference)
#define B_ 4
#define S_ 2048
#define D_ 1024
#define CCH 64                    // chunks along S
#define LCH 32                    // chunk length; CCH*LCH == S_
#define NELEM ((size_t)B_*S_*D_)  // 8388608
#define MROWS (B_*S_)             // 8192

typedef __attribute__((ext_vector_type(4))) float f32x4;
typedef __attribute__((ext_vector_type(8))) _Float16 f16x8;  // 8 x fp16 fragment

__device__ __forceinline__ ushort f2h(float v) {
  __half h = __float2half(v);
  return __builtin_bit_cast(ushort, h);
}
__device__ __forceinline__ float h2f(ushort u) {
  return __half2float(__builtin_bit_cast(__half, u));
}

__device__ __forceinline__ void gload16(const ushort* src, char* ldsdst) {
  __builtin_amdgcn_global_load_lds(
      (const __attribute__((address_space(1))) void*)src,
      (__attribute__((address_space(3))) void*)ldsdst, 16, 0, 0);
}

// ---------------- conversions ----------------

// x -> fp16 [M][1024]
__global__ void xhalf_kernel(const float* __restrict__ x, ushort* __restrict__ xh) {
  size_t i = ((size_t)blockIdx.x * blockDim.x + threadIdx.x) * 8;
  if (i >= NELEM) return;
  float4 a = *(const float4*)(x + i);
  float4 b = *(const float4*)(x + i + 4);
  ushort h[8] = {f2h(a.x), f2h(a.y), f2h(a.z), f2h(a.w),
                 f2h(b.x), f2h(b.y), f2h(b.z), f2h(b.w)};
  *(ushort4*)(xh + i) = *(ushort4*)h;
  *(ushort4*)(xh + i + 4) = *(ushort4*)(h + 4);
}

// Five D x D weights -> W5T[z][n][k] fp16 (transposed), one launch (z selects W).
__global__ void transpose5(const float* __restrict__ W0, const float* __restrict__ W1,
                           const float* __restrict__ W2, const float* __restrict__ W3,
                           const float* __restrict__ W4, ushort* __restrict__ Th) {
  __shared__ float tile[64][65];  // +1 pad: conflict-free column reads
  const int z = blockIdx.z;
  const float* W = (z == 0) ? W0 : (z == 1) ? W1 : (z == 2) ? W2 : (z == 3) ? W3 : W4;
  ushort* T = Th + (size_t)z * D_ * D_;
  const int k0 = blockIdx.x * 64, n0 = blockIdx.y * 64;
  const int tx = threadIdx.x & 63, ty = threadIdx.x >> 6;  // 64 x 4
#pragma unroll
  for (int i = 0; i < 16; ++i)
    tile[ty * 16 + i][tx] = W[(size_t)(k0 + ty * 16 + i) * D_ + n0 + tx];
  __syncthreads();
#pragma unroll
  for (int i = 0; i < 16; ++i) {
    const int nn = ty * 16 + i;
    T[(size_t)(n0 + nn) * D_ + k0 + tx] = f2h(tile[tx][nn]);
  }
}

// W [Kd][Nd] f32 -> Th[n*sh+k] fp16 (transposed). For W_out.
__global__ void transpose_convert(const float* __restrict__ W, ushort* __restrict__ Th, int sh,
                                  int Kd, int Nd) {
  __shared__ float tile[64][65];
  const int k0 = blockIdx.x * 64, n0 = blockIdx.y * 64;
  const int tx = threadIdx.x & 63, ty = threadIdx.x >> 6;
#pragma unroll
  for (int i = 0; i < 16; ++i)
    tile[ty * 16 + i][tx] = W[(size_t)(k0 + ty * 16 + i) * Nd + n0 + tx];
  __syncthreads();
#pragma unroll
  for (int i = 0; i < 16; ++i) {
    const int nn = ty * 16 + i;
    Th[(size_t)(n0 + nn) * sh + k0 + tx] = f2h(tile[tx][nn]);
  }
}

// ------- 128xBN fp16 MFMA GEMM, 16x16x32 fragments, BK=32, m97-style drain -------
// 8 waves (2m x 4n), wave tile 64x(BN/4). LDS: 2 slices x (8KB A + BN*64 B):
//   BN=256 -> 48KB (3 blocks/CU) ; BN=128 -> 32KB (4 blocks/CU).
// Cross-block overlap (multiple resident blocks, independent barriers) hides the
// per-tile vmcnt(0) drain [r13: 2 blocks/CU -> 859 TF]. Row-pair 128B lines,
// phys granule = ((row&1)*4 + kgran) ^ (line&7); conflicts = 0 (r7/r9/r11/r13).
// !FINAL: writes fp16 planes Ch (col>>10 selects plane; plane 4 -> C4h).
// FINAL: Cf = acc + xres + bias (fp32 out).
template <int FINAL, int BN>
__global__ __launch_bounds__(512, 2) void gemmT(
    const ushort* __restrict__ A, int lda, const ushort* __restrict__ Bw,
    ushort* __restrict__ Ch, ushort* __restrict__ C4h,
    float* __restrict__ Cf, const float* __restrict__ xres, const float* __restrict__ bias,
    int M, int K) {
  constexpr int SLICE = 8192 + BN * 64;  // A 8KB + B BN*64B
  constexpr int JJ = BN / 64;            // B frags per wave (4 or 2)
  __shared__ __align__(16) char ldsc[2 * SLICE];
  const int bid = blockIdx.x;
  const int tm = bid & 63, tn = bid >> 6;
  const int ldb = K;
  const int NT = K >> 5;
  const int t = threadIdx.x, lane = t & 63, wid = t >> 6;
  const int wm = wid >> 2, wn = wid & 3;

  f32x4 acc[4][JJ];
#pragma unroll
  for (int i = 0; i < 4; ++i)
#pragma unroll
    for (int j = 0; j < JJ; ++j) acc[i][j] = (f32x4){0.f, 0.f, 0.f, 0.f};

  // ---- staging: linear LDS dest t*16; inverse-swizzled global source ----
  const int line1 = t >> 3;
  const int g8s = (t & 7) ^ (line1 & 7);
  const int rowS = line1 * 2 + (g8s >> 2);   // 0..127
  const int kgS = (g8s & 3) << 3;
  const ushort* srcA = A + (size_t)(tm * 128 + rowS) * lda + kgS;
  const ushort* srcB = Bw + (size_t)(tn * BN + rowS) * ldb + kgS;
  char* dstA = ldsc + (size_t)t * 16;
  char* dstB = ldsc + 8192 + (size_t)t * 16;

  auto STAGE = [&](int tile, int slot) {
    const int ts = (tile < NT) ? tile : NT - 1;  // clamp: no OOB on last prefetch
    char* ba = dstA + slot * SLICE;
    char* bb = dstB + slot * SLICE;
    gload16(srcA + ts * 32, ba);
    gload16(srcB + ts * 32, bb);
    if (BN == 256) gload16(srcB + (size_t)128 * ldb + ts * 32, bb + 8192);
  };

  // ---- fragment reads (16x16x32): row = f*16 + lane15, kgran = lane>>4 ----
  const int lane15 = lane & 15;
  const int hl = lane15 >> 1;
  const int swz = ((((lane15 & 1) << 2) + (lane >> 4)) ^ hl) << 4;
  const char* aB = ldsc + wm * 4096 + hl * 128 + swz;
  const char* bB = ldsc + 8192 + wn * ((BN / 4) * 64) + hl * 128 + swz;

  STAGE(0, 0);
  asm volatile("s_waitcnt vmcnt(0)" ::: "memory");
  __builtin_amdgcn_sched_barrier(0);
  __builtin_amdgcn_s_barrier();

#pragma unroll 1
  for (int tt = 0; tt < NT; ++tt) {
    STAGE(tt + 1, (tt + 1) & 1);  // write the non-read slot (WAR-safe via prev barrier)
    const char* ab = aB + (tt & 1) * SLICE;
    const char* bb = bB + (tt & 1) * SLICE;
    f16x8 af[4], bf_[JJ];
#pragma unroll
    for (int f = 0; f < 4; ++f) af[f] = *(const f16x8*)(ab + f * 1024);
#pragma unroll
    for (int c = 0; c < JJ; ++c) bf_[c] = *(const f16x8*)(bb + c * 1024);
    asm volatile("s_waitcnt lgkmcnt(0)" ::: "memory");
    __builtin_amdgcn_sched_barrier(0);
    __builtin_amdgcn_s_setprio(1);
#pragma unroll
    for (int f = 0; f < 4; ++f)
#pragma unroll
      for (int c = 0; c < JJ; ++c)
        acc[f][c] = __builtin_amdgcn_mfma_f32_16x16x32_f16(af[f], bf_[c], acc[f][c], 0, 0, 0);
    __builtin_amdgcn_s_setprio(0);
    asm volatile("s_waitcnt vmcnt(0)" ::: "memory");  // tile tt+1 landed
    __builtin_amdgcn_sched_barrier(0);
    __builtin_amdgcn_s_barrier();
  }

  // epilogue. C/D layout: col=lane&15, row=(lane>>4)*4+reg  [m89-verified]
#pragma unroll
  for (int i = 0; i < 4; ++i) {
    const int row0 = tm * 128 + wm * 64 + i * 16 + ((lane >> 4) << 2);
#pragma unroll
    for (int jj = 0; jj < JJ; ++jj) {
      const int col = tn * BN + wn * (BN / 4) + jj * 16 + lane15;
      if (FINAL) {
#pragma unroll
        for (int r = 0; r < 4; ++r) {
          const size_t idx = (size_t)(row0 + r) * 1024 + col;
          Cf[idx] = acc[i][jj][r] + xres[idx] + bias[col];
        }
      } else {
        const int pl = col >> 10;
        ushort* base = (pl < 4) ? (Ch + (size_t)pl * (size_t)M * 1024) : C4h;
#pragma unroll
        for (int r = 0; r < 4; ++r)
          base[(size_t)(row0 + r) * 1024 + (col & 1023)] = f2h(acc[i][jj][r]);
      }
    }
  }
}

// ---------------- fused elementwise / scan passes (fp16 planes + fp16 x) ----------------

__device__ __forceinline__ void load4h(const ushort* p, float* f) {
  ushort4 u = *(const ushort4*)p;
  f[0] = h2f(u.x); f[1] = h2f(u.y); f[2] = h2f(u.z); f[3] = h2f(u.w);
}

// P1+P2: gating/sigmoid transforms in place (fp16) + per-(b,chunk,d) fp32 sums
__global__ void prep_chunk_kernel(ushort* __restrict__ omega_go, const ushort* __restrict__ gate_lin,
                                  ushort* __restrict__ mag_io,
                                  const float* __restrict__ b_om, const float* __restrict__ b_gate,
                                  const float* __restrict__ b_mag, const float* __restrict__ isc,
                                  float* __restrict__ gsum, float* __restrict__ msum) {
  int tid = blockIdx.x * blockDim.x + threadIdx.x;
  if (tid >= B_ * CCH * (D_ / 4)) return;
  int d4 = tid & 255, c = (tid >> 8) & (CCH - 1), b = tid >> 14;
  int d = d4 * 4;
  size_t base = ((size_t)(b * S_) + c * LCH) * D_ + d;
  size_t cs = ((size_t)(b * CCH) + c) * D_ + d;
  float bo[4], bg[4], bm[4], is[4];
  *(float4*)bo = *(const float4*)(b_om + d);
  *(float4*)bg = *(const float4*)(b_gate + d);
  *(float4*)bm = *(const float4*)(b_mag + d);
  *(float4*)is = *(const float4*)(isc + d);
  float sg[4] = {0.f, 0.f, 0.f, 0.f}, sm[4] = {0.f, 0.f, 0.f, 0.f};
  for (int s = 0; s < LCH; ++s) {
    size_t i = base + (size_t)s * D_;
    float om[4], gl[4], mg[4];
    load4h(omega_go + i, om);
    load4h(gate_lin + i, gl);
    load4h(mag_io + i, mg);
    ushort wo[4], wm_[4];
#pragma unroll
    for (int j = 0; j < 4; ++j) {
      float g = 1.f / (1.f + __expf(-(gl[j] + bg[j])));
      float m5 = 5.f / (1.f + __expf(-(mg[j] + bm[j])));
      float go = g * ((om[j] + bo[j]) * fabsf(is[j]));
      sg[j] += go;
      sm[j] += m5;
      wo[j] = f2h(go);
      wm_[j] = f2h(m5);
    }
    *(ushort4*)(omega_go + i) = *(ushort4*)wo;
    *(ushort4*)(mag_io + i) = *(ushort4*)wm_;
  }
  *(float4*)(gsum + cs) = *(float4*)sg;
  *(float4*)(msum + cs) = *(float4*)sm;
}

// P3/P5: exclusive scan of chunk totals along c — wave-parallel (lane = chunk)
__global__ void scan_offsets_kernel(float* __restrict__ s1, float* __restrict__ s2) {
  int gw = (blockIdx.x * blockDim.x + threadIdx.x) >> 6;
  int lane = threadIdx.x & 63;
  if (gw >= B_ * D_) return;
  int d = gw & (D_ - 1), b = gw >> 10;
  size_t idx = ((size_t)(b * CCH) + lane) * D_ + d;
  float v1 = s1[idx], v2 = s2[idx];
#pragma unroll
  for (int off = 1; off < 64; off <<= 1) {
    float u1 = __shfl_up(v1, off);
    float u2 = __shfl_up(v2, off);
    if (lane >= off) { v1 += u1; v2 += u2; }
  }
  float e1 = __shfl_up(v1, 1), e2 = __shfl_up(v2, 1);
  if (lane == 0) { e1 = 0.f; e2 = 0.f; }
  s1[idx] = e1;
  s2[idx] = e2;
}

// P4 (slim): chunked scan -> ctx parts 0,1 + tr/ti chunk totals. Planes untouched.
__global__ void phase_scan_kernel(const ushort* __restrict__ xh, const ushort* __restrict__ go,
                                  const ushort* __restrict__ mag, const ushort* __restrict__ p0,
                                  const float* __restrict__ goff,
                                  float* __restrict__ trsum, float* __restrict__ tisum,
                                  const float* __restrict__ b_phi, ushort* __restrict__ ctx) {
  int tid = blockIdx.x * blockDim.x + threadIdx.x;
  if (tid >= B_ * CCH * (D_ / 4)) return;
  int d4 = tid & 255, c = (tid >> 8) & (CCH - 1), b = tid >> 14;
  int d = d4 * 4;
  size_t base = ((size_t)(b * S_) + c * LCH) * D_ + d;
  size_t cs = ((size_t)(b * CCH) + c) * D_ + d;
  float pr[4], bp[4];
  *(float4*)pr = *(const float4*)(goff + cs);
  *(float4*)bp = *(const float4*)(b_phi + d);
  float tr[4] = {0.f, 0.f, 0.f, 0.f}, ti[4] = {0.f, 0.f, 0.f, 0.f};
  size_t crow = ((size_t)(b * S_ + c * LCH)) * 4096 + d;
  for (int s = 0; s < LCH; ++s) {
    size_t i = base + (size_t)s * D_;
    float g[4], ph0[4], m[4], xv[4];
    load4h(go + i, g);
    load4h(p0 + i, ph0);
    load4h(mag + i, m);
    load4h(xh + i, xv);
    ushort c4[4], s4[4];
#pragma unroll
    for (int j = 0; j < 4; ++j) {
      pr[j] += g[j];
      float ph = ph0[j] + bp[j] + pr[j];
      float sp, cp;
      __sincosf(ph, &sp, &cp);
      float wr = m[j] * xv[j];
      tr[j] += wr * cp;
      ti[j] += wr * sp;
      c4[j] = f2h(xv[j] * cp);
      s4[j] = f2h(xv[j] * sp);
    }
    *(ushort4*)(ctx + crow) = *(ushort4*)c4;
    *(ushort4*)(ctx + crow + 1024) = *(ushort4*)s4;
    crow += 4096;
  }
  *(float4*)(trsum + cs) = *(float4*)tr;
  *(float4*)(tisum + cs) = *(float4*)ti;
}

// P6 (recompute): re-run the chunk chains, normalize + retrieve -> ctx parts 2,3
__global__ void retrieve_kernel(const ushort* __restrict__ xh, const ushort* __restrict__ go,
                                const ushort* __restrict__ mag, const ushort* __restrict__ p0,
                                const ushort* __restrict__ q,
                                const float* __restrict__ goff, const float* __restrict__ moff,
                                const float* __restrict__ troff, const float* __restrict__ tioff,
                                const float* __restrict__ b_phi, const float* __restrict__ b_q,
                                ushort* __restrict__ ctx) {
  int tid = blockIdx.x * blockDim.x + threadIdx.x;
  if (tid >= B_ * CCH * (D_ / 4)) return;
  int d4 = tid & 255, c = (tid >> 8) & (CCH - 1), b = tid >> 14;
  int d = d4 * 4;
  size_t base = ((size_t)(b * S_) + c * LCH) * D_ + d;
  size_t cs = ((size_t)(b * CCH) + c) * D_ + d;
  float pr[4], mr[4], tr[4], ti[4], bp[4], bq[4];
  *(float4*)pr = *(const float4*)(goff + cs);
  *(float4*)mr = *(const float4*)(moff + cs);
  *(float4*)tr = *(const float4*)(troff + cs);
  *(float4*)ti = *(const float4*)(tioff + cs);
  *(float4*)bp = *(const float4*)(b_phi + d);
  *(float4*)bq = *(const float4*)(b_q + d);
  size_t crow = ((size_t)(b * S_ + c * LCH)) * 4096 + d;
  for (int s = 0; s < LCH; ++s) {
    size_t i = base + (size_t)s * D_;
    float g[4], ph0[4], m[4], xv[4], qv[4];
    load4h(go + i, g);
    load4h(p0 + i, ph0);
    load4h(mag + i, m);
    load4h(q + i, qv);
    load4h(xh + i, xv);
    ushort r2[4], r3[4];
#pragma unroll
    for (int j = 0; j < 4; ++j) {
      pr[j] += g[j];
      float ph = ph0[j] + bp[j] + pr[j];
      float sp, cp;
      __sincosf(ph, &sp, &cp);
      mr[j] += m[j];
      float wr = m[j] * xv[j];
      tr[j] += wr * cp;
      ti[j] += wr * sp;
      float rs = rsqrtf(mr[j] + 1e-8f);
      float mreal = tr[j] * rs, mimag = ti[j] * rs;
      float phq = ph + qv[j] + bq[j];
      float sq, cq;
      __sincosf(phq, &sq, &cq);
      r2[j] = f2h(mreal * cq + mimag * sq);
      r3[j] = f2h(mimag * cq - mreal * sq);
    }
    *(ushort4*)(ctx + crow + 2048) = *(ushort4*)r2;
    *(ushort4*)(ctx + crow + 3072) = *(ushort4*)r3;
    crow += 4096;
  }
}

// ---------------- launcher ----------------
extern "C" void kernel_launch(void* const* d_in, const int* in_sizes, int n_in,
                              void* d_out, int out_size, void* d_ws, size_t ws_size,
                              hipStream_t stream) {
  const float* x      = (const float*)d_in[0];
  const float* W_om   = (const float*)d_in[1];
  const float* b_om   = (const float*)d_in[2];
  const float* W_mag  = (const float*)d_in[3];
  const float* b_mag  = (const float*)d_in[4];
  const float* W_phi  = (const float*)d_in[5];
  const float* b_phi  = (const float*)d_in[6];
  const float* W_gate = (const float*)d_in[7];
  const float* b_gate = (const float*)d_in[8];
  const float* W_q    = (const float*)d_in[9];
  const float* b_q    = (const float*)d_in[10];
  const float* isc    = (const float*)d_in[11];
  const float* W_out  = (const float*)d_in[12];
  const float* b_out  = (const float*)d_in[13];
  float* out = (float*)d_out;

  // ---- ws layout, 213,909,504 bytes ----
  // [0, 67108864)          4 fp16 planes: omega|gate|mag|phi0
  // [67108864, 83886080)   x_h fp16 [8192][1024] (lives through retrieve)
  // [134217728, 201326592) ctx fp16 [8192][4096]; W5T (10.5MB, dead after GEMM1)
  //                        overlapped at +16777216
  // [201326592)            WoutT [1024][4096] fp16
  // [209715200)            gsum|msum|trsum|tisum (4 x 1MB)
  // q_lin (fp16) lives in d_out (overwritten by the final GEMM afterwards).
  const size_t WS_NEEDED = 213909504ull;
  if (ws_size < WS_NEEDED) {
    (void)hipMemsetAsync(d_out, 0, (size_t)out_size * sizeof(float), stream);
    return;
  }
  char* w = (char*)d_ws;
  ushort* planes_h = (ushort*)w;                      // 4 x NELEM fp16
  ushort* omega_buf = planes_h;
  ushort* gate_buf  = planes_h + NELEM;
  ushort* mag_buf   = planes_h + 2 * NELEM;
  ushort* phi0_buf  = planes_h + 3 * NELEM;
  ushort* x_h   = (ushort*)(w + 67108864);            // [8192][1024] fp16
  ushort* q_buf = (ushort*)out;                       // fp16 q plane in d_out
  char* ctxb = w + 4 * NELEM * 4;
  ushort* ctx   = (ushort*)ctxb;
  ushort* W5T   = (ushort*)(ctxb + 16777216);         // [5120][1024]: om|gate|mag|phi0|q
  ushort* WoutT = (ushort*)(w + 201326592);           // [1024][4096]
  float* gsum  = (float*)(w + 209715200);
  float* msum  = (float*)(w + 210763776);
  float* trsum = (float*)(w + 211812352);
  float* tisum = (float*)(w + 212860928);

  // conversions (batched)
  xhalf_kernel<<<(int)(NELEM / 2048), 256, 0, stream>>>(x, x_h);
  transpose5<<<dim3(16, 16, 5), 256, 0, stream>>>(W_om, W_gate, W_mag, W_phi, W_q, W5T);
  transpose_convert<<<dim3(64, 16), 256, 0, stream>>>(W_out, WoutT, 4096, 4 * D_, D_);

  // GEMM1: 5 projections, N=5120, K=1024. 1280 blocks (5 exact rounds),
  // 48KB LDS -> 3 blocks/CU resident.
  gemmT<0, 256><<<1280, 512, 0, stream>>>(x_h, 1024, W5T, planes_h, q_buf,
                                          nullptr, nullptr, nullptr, MROWS, 1024);

  // scans + fused elementwise
  prep_chunk_kernel<<<B_ * CCH * (D_ / 4) / 256, 256, 0, stream>>>(
      omega_buf, gate_buf, mag_buf, b_om, b_gate, b_mag, isc, gsum, msum);
  scan_offsets_kernel<<<B_ * D_ * 64 / 256, 256, 0, stream>>>(gsum, msum);
  phase_scan_kernel<<<B_ * CCH * (D_ / 4) / 256, 256, 0, stream>>>(
      x_h, omega_buf, mag_buf, phi0_buf, gsum, trsum, tisum, b_phi, ctx);
  scan_offsets_kernel<<<B_ * D_ * 64 / 256, 256, 0, stream>>>(trsum, tisum);
  retrieve_kernel<<<B_ * CCH * (D_ / 4) / 256, 256, 0, stream>>>(
      x_h, omega_buf, mag_buf, phi0_buf, q_buf, gsum, msum, trsum, tisum, b_phi, b_q, ctx);

  // final: out = x + ctx @ W_out + b_out. 128x128 tiles -> 512 blocks,
  // 32KB LDS -> 4 blocks/CU; no split-K, no add pass.
  gemmT<1, 128><<<512, 512, 0, stream>>>(ctx, 4096, WoutT, nullptr, nullptr, out,
                                         x, b_out, MROWS, 4 * D_);
}

// Round 15
// 300.151 us; speedup vs baseline: 1.0139x; 1.0139x over previous
//
#include <hip/hip_runtime.h>
#include <hip/hip_fp16.h>

// Problem constants (B,S,D fixed by the reference)
#define B_ 4
#define S_ 2048
#define D_ 1024
#define CCH 64                    // chunks along S
#define LCH 32                    // chunk length; CCH*LCH == S_
#define NELEM ((size_t)B_*S_*D_)  // 8388608
#define MROWS (B_*S_)             // 8192

typedef __attribute__((ext_vector_type(4))) float f32x4;
typedef __attribute__((ext_vector_type(8))) _Float16 f16x8;  // 8 x fp16 fragment

__device__ __forceinline__ ushort f2h(float v) {
  __half h = __float2half(v);
  return __builtin_bit_cast(ushort, h);
}
__device__ __forceinline__ float h2f(ushort u) {
  return __half2float(__builtin_bit_cast(__half, u));
}

__device__ __forceinline__ void gload16(const ushort* src, char* ldsdst) {
  __builtin_amdgcn_global_load_lds(
      (const __attribute__((address_space(1))) void*)src,
      (__attribute__((address_space(3))) void*)ldsdst, 16, 0, 0);
}

// ---------------- conversions ----------------

// x -> fp16 [M][1024]
__global__ void xhalf_kernel(const float* __restrict__ x, ushort* __restrict__ xh) {
  size_t i = ((size_t)blockIdx.x * blockDim.x + threadIdx.x) * 8;
  if (i >= NELEM) return;
  float4 a = *(const float4*)(x + i);
  float4 b = *(const float4*)(x + i + 4);
  ushort h[8] = {f2h(a.x), f2h(a.y), f2h(a.z), f2h(a.w),
                 f2h(b.x), f2h(b.y), f2h(b.z), f2h(b.w)};
  *(ushort4*)(xh + i) = *(ushort4*)h;
  *(ushort4*)(xh + i + 4) = *(ushort4*)(h + 4);
}

// Five D x D weights -> W5T[z][n][k] fp16 (transposed), one launch (z selects W).
__global__ void transpose5(const float* __restrict__ W0, const float* __restrict__ W1,
                           const float* __restrict__ W2, const float* __restrict__ W3,
                           const float* __restrict__ W4, ushort* __restrict__ Th) {
  __shared__ float tile[64][65];  // +1 pad: conflict-free column reads
  const int z = blockIdx.z;
  const float* W = (z == 0) ? W0 : (z == 1) ? W1 : (z == 2) ? W2 : (z == 3) ? W3 : W4;
  ushort* T = Th + (size_t)z * D_ * D_;
  const int k0 = blockIdx.x * 64, n0 = blockIdx.y * 64;
  const int tx = threadIdx.x & 63, ty = threadIdx.x >> 6;  // 64 x 4
#pragma unroll
  for (int i = 0; i < 16; ++i)
    tile[ty * 16 + i][tx] = W[(size_t)(k0 + ty * 16 + i) * D_ + n0 + tx];
  __syncthreads();
#pragma unroll
  for (int i = 0; i < 16; ++i) {
    const int nn = ty * 16 + i;
    T[(size_t)(n0 + nn) * D_ + k0 + tx] = f2h(tile[tx][nn]);
  }
}

// W [Kd][Nd] f32 -> Th[n*sh+k] fp16 (transposed). For W_out.
__global__ void transpose_convert(const float* __restrict__ W, ushort* __restrict__ Th, int sh,
                                  int Kd, int Nd) {
  __shared__ float tile[64][65];
  const int k0 = blockIdx.x * 64, n0 = blockIdx.y * 64;
  const int tx = threadIdx.x & 63, ty = threadIdx.x >> 6;
#pragma unroll
  for (int i = 0; i < 16; ++i)
    tile[ty * 16 + i][tx] = W[(size_t)(k0 + ty * 16 + i) * Nd + n0 + tx];
  __syncthreads();
#pragma unroll
  for (int i = 0; i < 16; ++i) {
    const int nn = ty * 16 + i;
    Th[(size_t)(n0 + nn) * sh + k0 + tx] = f2h(tile[tx][nn]);
  }
}

// ------- 128xBN fp16 MFMA GEMM, 16x16x32 fragments, BK=32 -------
// 8 waves (2m x 4n), wave tile 64x(BN/4). LDS: 3 slice buffers:
//   BN=256 -> 3 x 24KB = 72KB (2 blocks/CU via grid); BN=128 -> 3 x 16KB = 48KB.
// r13-proven depth-2 counted pipeline: prologue stages tiles 0,1; iter tt
// issues STAGE(tt+2) (clamped: fixed load count); end-of-tile wait
// vmcnt(LOADS) — tile tt+1 landed, next stage's loads stay in flight.
// Cross-block overlap (>=2 resident blocks/CU) hides the barrier stall
// [r13: 859 TF measured]. Row-pair 128B lines, phys granule =
// ((row&1)*4 + kgran) ^ (line&7); conflicts = 0 (r7/r9/r11/r13).
// !FINAL: writes fp16 planes Ch (col>>10 selects plane; plane 4 -> C4h).
// FINAL: Cf = acc + xres + bias (fp32 out).
template <int FINAL, int BN>
__global__ __launch_bounds__(512, 2) void gemmT(
    const ushort* __restrict__ A, int lda, const ushort* __restrict__ Bw,
    ushort* __restrict__ Ch, ushort* __restrict__ C4h,
    float* __restrict__ Cf, const float* __restrict__ xres, const float* __restrict__ bias,
    int M, int K) {
  constexpr int SLICE = 8192 + BN * 64;  // A 8KB + B BN*64B
  constexpr int JJ = BN / 64;            // B frags per wave (4 or 2)
  __shared__ __align__(16) char ldsc[3 * SLICE];
  const int bid = blockIdx.x;
  const int tm = bid & 63, tn = bid >> 6;
  const int ldb = K;
  const int NT = K >> 5;
  const int t = threadIdx.x, lane = t & 63, wid = t >> 6;
  const int wm = wid >> 2, wn = wid & 3;

  f32x4 acc[4][JJ];
#pragma unroll
  for (int i = 0; i < 4; ++i)
#pragma unroll
    for (int j = 0; j < JJ; ++j) acc[i][j] = (f32x4){0.f, 0.f, 0.f, 0.f};

  // ---- staging: linear LDS dest t*16; inverse-swizzled global source ----
  const int line1 = t >> 3;
  const int g8s = (t & 7) ^ (line1 & 7);
  const int rowS = line1 * 2 + (g8s >> 2);   // 0..127
  const int kgS = (g8s & 3) << 3;
  const ushort* srcA = A + (size_t)(tm * 128 + rowS) * lda + kgS;
  const ushort* srcB = Bw + (size_t)(tn * BN + rowS) * ldb + kgS;
  char* dstA = ldsc + (size_t)t * 16;
  char* dstB = ldsc + 8192 + (size_t)t * 16;

  auto STAGE = [&](int tile, int slot) {
    const int ts = (tile < NT) ? tile : NT - 1;  // clamp: fixed load count
    char* ba = dstA + slot * SLICE;
    char* bb = dstB + slot * SLICE;
    gload16(srcA + ts * 32, ba);
    gload16(srcB + ts * 32, bb);
    if (BN == 256) gload16(srcB + (size_t)128 * ldb + ts * 32, bb + 8192);
  };
#define WAIT_OLDEST()                                               \
  if (BN == 256) { asm volatile("s_waitcnt vmcnt(3)" ::: "memory"); } \
  else           { asm volatile("s_waitcnt vmcnt(2)" ::: "memory"); }

  // ---- fragment reads (16x16x32): row = f*16 + lane15, kgran = lane>>4 ----
  const int lane15 = lane & 15;
  const int hl = lane15 >> 1;
  const int swz = ((((lane15 & 1) << 2) + (lane >> 4)) ^ hl) << 4;
  const char* aB = ldsc + wm * 4096 + hl * 128 + swz;
  const char* bB = ldsc + 8192 + wn * ((BN / 4) * 64) + hl * 128 + swz;

  // prologue: 2 tiles staged; wait for tile 0 only
  STAGE(0, 0); STAGE(1, 1);
  WAIT_OLDEST();
  __builtin_amdgcn_sched_barrier(0);
  __builtin_amdgcn_s_barrier();

  int s_rd = 0, s_st = 2;
#pragma unroll 1
  for (int tt = 0; tt < NT; ++tt) {
    STAGE(tt + 2, s_st);  // in flight: tiles tt+1, tt+2
    const char* ab = aB + s_rd * SLICE;
    const char* bb = bB + s_rd * SLICE;
    f16x8 af[4], bf_[JJ];
#pragma unroll
    for (int f = 0; f < 4; ++f) af[f] = *(const f16x8*)(ab + f * 1024);
#pragma unroll
    for (int c = 0; c < JJ; ++c) bf_[c] = *(const f16x8*)(bb + c * 1024);
    asm volatile("s_waitcnt lgkmcnt(0)" ::: "memory");
    __builtin_amdgcn_sched_barrier(0);
    __builtin_amdgcn_s_setprio(1);
#pragma unroll
    for (int f = 0; f < 4; ++f)
#pragma unroll
      for (int c = 0; c < JJ; ++c)
        acc[f][c] = __builtin_amdgcn_mfma_f32_16x16x32_f16(af[f], bf_[c], acc[f][c], 0, 0, 0);
    __builtin_amdgcn_s_setprio(0);
    WAIT_OLDEST();  // tile tt+1 landed; next stage stays in flight
    __builtin_amdgcn_sched_barrier(0);
    __builtin_amdgcn_s_barrier();
    s_rd = (s_rd == 2) ? 0 : s_rd + 1;
    s_st = (s_st == 2) ? 0 : s_st + 1;
  }
#undef WAIT_OLDEST

  // epilogue. C/D layout: col=lane&15, row=(lane>>4)*4+reg  [m89-verified]
#pragma unroll
  for (int i = 0; i < 4; ++i) {
    const int row0 = tm * 128 + wm * 64 + i * 16 + ((lane >> 4) << 2);
#pragma unroll
    for (int jj = 0; jj < JJ; ++jj) {
      const int col = tn * BN + wn * (BN / 4) + jj * 16 + lane15;
      if (FINAL) {
#pragma unroll
        for (int r = 0; r < 4; ++r) {
          const size_t idx = (size_t)(row0 + r) * 1024 + col;
          Cf[idx] = acc[i][jj][r] + xres[idx] + bias[col];
        }
      } else {
        const int pl = col >> 10;
        ushort* base = (pl < 4) ? (Ch + (size_t)pl * (size_t)M * 1024) : C4h;
#pragma unroll
        for (int r = 0; r < 4; ++r)
          base[(size_t)(row0 + r) * 1024 + (col & 1023)] = f2h(acc[i][jj][r]);
      }
    }
  }
}

// ---------------- fused elementwise / scan passes (fp16 planes + fp16 x) ----------------

__device__ __forceinline__ void load4h(const ushort* p, float* f) {
  ushort4 u = *(const ushort4*)p;
  f[0] = h2f(u.x); f[1] = h2f(u.y); f[2] = h2f(u.z); f[3] = h2f(u.w);
}

// P1+P2: gating/sigmoid transforms in place (fp16) + per-(b,chunk,d) fp32 sums
__global__ void prep_chunk_kernel(ushort* __restrict__ omega_go, const ushort* __restrict__ gate_lin,
                                  ushort* __restrict__ mag_io,
                                  const float* __restrict__ b_om, const float* __restrict__ b_gate,
                                  const float* __restrict__ b_mag, const float* __restrict__ isc,
                                  float* __restrict__ gsum, float* __restrict__ msum) {
  int tid = blockIdx.x * blockDim.x + threadIdx.x;
  if (tid >= B_ * CCH * (D_ / 4)) return;
  int d4 = tid & 255, c = (tid >> 8) & (CCH - 1), b = tid >> 14;
  int d = d4 * 4;
  size_t base = ((size_t)(b * S_) + c * LCH) * D_ + d;
  size_t cs = ((size_t)(b * CCH) + c) * D_ + d;
  float bo[4], bg[4], bm[4], is[4];
  *(float4*)bo = *(const float4*)(b_om + d);
  *(float4*)bg = *(const float4*)(b_gate + d);
  *(float4*)bm = *(const float4*)(b_mag + d);
  *(float4*)is = *(const float4*)(isc + d);
  float sg[4] = {0.f, 0.f, 0.f, 0.f}, sm[4] = {0.f, 0.f, 0.f, 0.f};
  for (int s = 0; s < LCH; ++s) {
    size_t i = base + (size_t)s * D_;
    float om[4], gl[4], mg[4];
    load4h(omega_go + i, om);
    load4h(gate_lin + i, gl);
    load4h(mag_io + i, mg);
    ushort wo[4], wm_[4];
#pragma unroll
    for (int j = 0; j < 4; ++j) {
      float g = 1.f / (1.f + __expf(-(gl[j] + bg[j])));
      float m5 = 5.f / (1.f + __expf(-(mg[j] + bm[j])));
      float go = g * ((om[j] + bo[j]) * fabsf(is[j]));
      sg[j] += go;
      sm[j] += m5;
      wo[j] = f2h(go);
      wm_[j] = f2h(m5);
    }
    *(ushort4*)(omega_go + i) = *(ushort4*)wo;
    *(ushort4*)(mag_io + i) = *(ushort4*)wm_;
  }
  *(float4*)(gsum + cs) = *(float4*)sg;
  *(float4*)(msum + cs) = *(float4*)sm;
}

// P3/P5: exclusive scan of chunk totals along c — wave-parallel (lane = chunk)
__global__ void scan_offsets_kernel(float* __restrict__ s1, float* __restrict__ s2) {
  int gw = (blockIdx.x * blockDim.x + threadIdx.x) >> 6;
  int lane = threadIdx.x & 63;
  if (gw >= B_ * D_) return;
  int d = gw & (D_ - 1), b = gw >> 10;
  size_t idx = ((size_t)(b * CCH) + lane) * D_ + d;
  float v1 = s1[idx], v2 = s2[idx];
#pragma unroll
  for (int off = 1; off < 64; off <<= 1) {
    float u1 = __shfl_up(v1, off);
    float u2 = __shfl_up(v2, off);
    if (lane >= off) { v1 += u1; v2 += u2; }
  }
  float e1 = __shfl_up(v1, 1), e2 = __shfl_up(v2, 1);
  if (lane == 0) { e1 = 0.f; e2 = 0.f; }
  s1[idx] = e1;
  s2[idx] = e2;
}

// P4 (slim): chunked scan -> ctx parts 0,1 + tr/ti chunk totals. Planes untouched.
__global__ void phase_scan_kernel(const ushort* __restrict__ xh, const ushort* __restrict__ go,
                                  const ushort* __restrict__ mag, const ushort* __restrict__ p0,
                                  const float* __restrict__ goff,
                                  float* __restrict__ trsum, float* __restrict__ tisum,
                                  const float* __restrict__ b_phi, ushort* __restrict__ ctx) {
  int tid = blockIdx.x * blockDim.x + threadIdx.x;
  if (tid >= B_ * CCH * (D_ / 4)) return;
  int d4 = tid & 255, c = (tid >> 8) & (CCH - 1), b = tid >> 14;
  int d = d4 * 4;
  size_t base = ((size_t)(b * S_) + c * LCH) * D_ + d;
  size_t cs = ((size_t)(b * CCH) + c) * D_ + d;
  float pr[4], bp[4];
  *(float4*)pr = *(const float4*)(goff + cs);
  *(float4*)bp = *(const float4*)(b_phi + d);
  float tr[4] = {0.f, 0.f, 0.f, 0.f}, ti[4] = {0.f, 0.f, 0.f, 0.f};
  size_t crow = ((size_t)(b * S_ + c * LCH)) * 4096 + d;
  for (int s = 0; s < LCH; ++s) {
    size_t i = base + (size_t)s * D_;
    float g[4], ph0[4], m[4], xv[4];
    load4h(go + i, g);
    load4h(p0 + i, ph0);
    load4h(mag + i, m);
    load4h(xh + i, xv);
    ushort c4[4], s4[4];
#pragma unroll
    for (int j = 0; j < 4; ++j) {
      pr[j] += g[j];
      float ph = ph0[j] + bp[j] + pr[j];
      float sp, cp;
      __sincosf(ph, &sp, &cp);
      float wr = m[j] * xv[j];
      tr[j] += wr * cp;
      ti[j] += wr * sp;
      c4[j] = f2h(xv[j] * cp);
      s4[j] = f2h(xv[j] * sp);
    }
    *(ushort4*)(ctx + crow) = *(ushort4*)c4;
    *(ushort4*)(ctx + crow + 1024) = *(ushort4*)s4;
    crow += 4096;
  }
  *(float4*)(trsum + cs) = *(float4*)tr;
  *(float4*)(tisum + cs) = *(float4*)ti;
}

// P6 (recompute): re-run the chunk chains, normalize + retrieve -> ctx parts 2,3
__global__ void retrieve_kernel(const ushort* __restrict__ xh, const ushort* __restrict__ go,
                                const ushort* __restrict__ mag, const ushort* __restrict__ p0,
                                const ushort* __restrict__ q,
                                const float* __restrict__ goff, const float* __restrict__ moff,
                                const float* __restrict__ troff, const float* __restrict__ tioff,
                                const float* __restrict__ b_phi, const float* __restrict__ b_q,
                                ushort* __restrict__ ctx) {
  int tid = blockIdx.x * blockDim.x + threadIdx.x;
  if (tid >= B_ * CCH * (D_ / 4)) return;
  int d4 = tid & 255, c = (tid >> 8) & (CCH - 1), b = tid >> 14;
  int d = d4 * 4;
  size_t base = ((size_t)(b * S_) + c * LCH) * D_ + d;
  size_t cs = ((size_t)(b * CCH) + c) * D_ + d;
  float pr[4], mr[4], tr[4], ti[4], bp[4], bq[4];
  *(float4*)pr = *(const float4*)(goff + cs);
  *(float4*)mr = *(const float4*)(moff + cs);
  *(float4*)tr = *(const float4*)(troff + cs);
  *(float4*)ti = *(const float4*)(tioff + cs);
  *(float4*)bp = *(const float4*)(b_phi + d);
  *(float4*)bq = *(const float4*)(b_q + d);
  size_t crow = ((size_t)(b * S_ + c * LCH)) * 4096 + d;
  for (int s = 0; s < LCH; ++s) {
    size_t i = base + (size_t)s * D_;
    float g[4], ph0[4], m[4], xv[4], qv[4];
    load4h(go + i, g);
    load4h(p0 + i, ph0);
    load4h(mag + i, m);
    load4h(q + i, qv);
    load4h(xh + i, xv);
    ushort r2[4], r3[4];
#pragma unroll
    for (int j = 0; j < 4; ++j) {
      pr[j] += g[j];
      float ph = ph0[j] + bp[j] + pr[j];
      float sp, cp;
      __sincosf(ph, &sp, &cp);
      mr[j] += m[j];
      float wr = m[j] * xv[j];
      tr[j] += wr * cp;
      ti[j] += wr * sp;
      float rs = rsqrtf(mr[j] + 1e-8f);
      float mreal = tr[j] * rs, mimag = ti[j] * rs;
      float phq = ph + qv[j] + bq[j];
      float sq, cq;
      __sincosf(phq, &sq, &cq);
      r2[j] = f2h(mreal * cq + mimag * sq);
      r3[j] = f2h(mimag * cq - mreal * sq);
    }
    *(ushort4*)(ctx + crow + 2048) = *(ushort4*)r2;
    *(ushort4*)(ctx + crow + 3072) = *(ushort4*)r3;
    crow += 4096;
  }
}

// ---------------- launcher ----------------
extern "C" void kernel_launch(void* const* d_in, const int* in_sizes, int n_in,
                              void* d_out, int out_size, void* d_ws, size_t ws_size,
                              hipStream_t stream) {
  const float* x      = (const float*)d_in[0];
  const float* W_om   = (const float*)d_in[1];
  const float* b_om   = (const float*)d_in[2];
  const float* W_mag  = (const float*)d_in[3];
  const float* b_mag  = (const float*)d_in[4];
  const float* W_phi  = (const float*)d_in[5];
  const float* b_phi  = (const float*)d_in[6];
  const float* W_gate = (const float*)d_in[7];
  const float* b_gate = (const float*)d_in[8];
  const float* W_q    = (const float*)d_in[9];
  const float* b_q    = (const float*)d_in[10];
  const float* isc    = (const float*)d_in[11];
  const float* W_out  = (const float*)d_in[12];
  const float* b_out  = (const float*)d_in[13];
  float* out = (float*)d_out;

  // ---- ws layout, 213,909,504 bytes ----
  // [0, 67108864)          4 fp16 planes: omega|gate|mag|phi0
  // [67108864, 83886080)   x_h fp16 [8192][1024] (lives through retrieve)
  // [134217728, 201326592) ctx fp16 [8192][4096]; W5T (10.5MB, dead after GEMM1)
  //                        overlapped at +16777216
  // [201326592)            WoutT [1024][4096] fp16
  // [209715200)            gsum|msum|trsum|tisum (4 x 1MB)
  // q_lin (fp16) lives in d_out (overwritten by the final GEMM afterwards).
  const size_t WS_NEEDED = 213909504ull;
  if (ws_size < WS_NEEDED) {
    (void)hipMemsetAsync(d_out, 0, (size_t)out_size * sizeof(float), stream);
    return;
  }
  char* w = (char*)d_ws;
  ushort* planes_h = (ushort*)w;                      // 4 x NELEM fp16
  ushort* omega_buf = planes_h;
  ushort* gate_buf  = planes_h + NELEM;
  ushort* mag_buf   = planes_h + 2 * NELEM;
  ushort* phi0_buf  = planes_h + 3 * NELEM;
  ushort* x_h   = (ushort*)(w + 67108864);            // [8192][1024] fp16
  ushort* q_buf = (ushort*)out;                       // fp16 q plane in d_out
  char* ctxb = w + 4 * NELEM * 4;
  ushort* ctx   = (ushort*)ctxb;
  ushort* W5T   = (ushort*)(ctxb + 16777216);         // [5120][1024]: om|gate|mag|phi0|q
  ushort* WoutT = (ushort*)(w + 201326592);           // [1024][4096]
  float* gsum  = (float*)(w + 209715200);
  float* msum  = (float*)(w + 210763776);
  float* trsum = (float*)(w + 211812352);
  float* tisum = (float*)(w + 212860928);

  // conversions (batched)
  xhalf_kernel<<<(int)(NELEM / 2048), 256, 0, stream>>>(x, x_h);
  transpose5<<<dim3(16, 16, 5), 256, 0, stream>>>(W_om, W_gate, W_mag, W_phi, W_q, W5T);
  transpose_convert<<<dim3(64, 16), 256, 0, stream>>>(W_out, WoutT, 4096, 4 * D_, D_);

  // GEMM1: 5 projections, N=5120, K=1024. 1280 blocks (5 exact rounds),
  // 72KB LDS -> 2 blocks/CU resident (r13 config: 859 TF).
  gemmT<0, 256><<<1280, 512, 0, stream>>>(x_h, 1024, W5T, planes_h, q_buf,
                                          nullptr, nullptr, nullptr, MROWS, 1024);

  // scans + fused elementwise
  prep_chunk_kernel<<<B_ * CCH * (D_ / 4) / 256, 256, 0, stream>>>(
      omega_buf, gate_buf, mag_buf, b_om, b_gate, b_mag, isc, gsum, msum);
  scan_offsets_kernel<<<B_ * D_ * 64 / 256, 256, 0, stream>>>(gsum, msum);
  phase_scan_kernel<<<B_ * CCH * (D_ / 4) / 256, 256, 0, stream>>>(
      x_h, omega_buf, mag_buf, phi0_buf, gsum, trsum, tisum, b_phi, ctx);
  scan_offsets_kernel<<<B_ * D_ * 64 / 256, 256, 0, stream>>>(trsum, tisum);
  retrieve_kernel<<<B_ * CCH * (D_ / 4) / 256, 256, 0, stream>>>(
      x_h, omega_buf, mag_buf, phi0_buf, q_buf, gsum, msum, trsum, tisum, b_phi, b_q, ctx);

  // final: out = x + ctx @ W_out + b_out. BN=128 -> 512 blocks, 48KB LDS
  // -> 2 blocks/CU resident, same counted pipeline.
  gemmT<1, 128><<<512, 512, 0, stream>>>(ctx, 4096, WoutT, nullptr, nullptr, out,
                                         x, b_out, MROWS, 4 * D_);
}

// Round 16
// 287.349 us; speedup vs baseline: 1.0591x; 1.0446x over previous
//
#include <hip/hip_runtime.h>
#include <hip/hip_fp16.h>

// Problem constants (B,S,D fixed by the reference)
#define B_ 4
#define S_ 2048
#define D_ 1024
#define CCH 128                   // chunks along S (r16: doubled for occupancy)
#define LCH 16                    // chunk length; CCH*LCH == S_
#define NELEM ((size_t)B_*S_*D_)  // 8388608
#define MROWS (B_*S_)             // 8192

typedef __attribute__((ext_vector_type(4))) float f32x4;
typedef __attribute__((ext_vector_type(8))) _Float16 f16x8;  // 8 x fp16 fragment

__device__ __forceinline__ ushort f2h(float v) {
  __half h = __float2half(v);
  return __builtin_bit_cast(ushort, h);
}
__device__ __forceinline__ float h2f(ushort u) {
  return __half2float(__builtin_bit_cast(__half, u));
}

__device__ __forceinline__ void gload16(const ushort* src, char* ldsdst) {
  __builtin_amdgcn_global_load_lds(
      (const __attribute__((address_space(1))) void*)src,
      (__attribute__((address_space(3))) void*)ldsdst, 16, 0, 0);
}

// ---------------- conversions ----------------

// x -> fp16 [M][1024]
__global__ void xhalf_kernel(const float* __restrict__ x, ushort* __restrict__ xh) {
  size_t i = ((size_t)blockIdx.x * blockDim.x + threadIdx.x) * 8;
  if (i >= NELEM) return;
  float4 a = *(const float4*)(x + i);
  float4 b = *(const float4*)(x + i + 4);
  ushort h[8] = {f2h(a.x), f2h(a.y), f2h(a.z), f2h(a.w),
                 f2h(b.x), f2h(b.y), f2h(b.z), f2h(b.w)};
  *(ushort4*)(xh + i) = *(ushort4*)h;
  *(ushort4*)(xh + i + 4) = *(ushort4*)(h + 4);
}

// Five D x D weights -> W5T[z][n][k] fp16 (transposed), one launch (z selects W).
__global__ void transpose5(const float* __restrict__ W0, const float* __restrict__ W1,
                           const float* __restrict__ W2, const float* __restrict__ W3,
                           const float* __restrict__ W4, ushort* __restrict__ Th) {
  __shared__ float tile[64][65];  // +1 pad: conflict-free column reads
  const int z = blockIdx.z;
  const float* W = (z == 0) ? W0 : (z == 1) ? W1 : (z == 2) ? W2 : (z == 3) ? W3 : W4;
  ushort* T = Th + (size_t)z * D_ * D_;
  const int k0 = blockIdx.x * 64, n0 = blockIdx.y * 64;
  const int tx = threadIdx.x & 63, ty = threadIdx.x >> 6;  // 64 x 4
#pragma unroll
  for (int i = 0; i < 16; ++i)
    tile[ty * 16 + i][tx] = W[(size_t)(k0 + ty * 16 + i) * D_ + n0 + tx];
  __syncthreads();
#pragma unroll
  for (int i = 0; i < 16; ++i) {
    const int nn = ty * 16 + i;
    T[(size_t)(n0 + nn) * D_ + k0 + tx] = f2h(tile[tx][nn]);
  }
}

// W [Kd][Nd] f32 -> Th[n*sh+k] fp16 (transposed). For W_out.
__global__ void transpose_convert(const float* __restrict__ W, ushort* __restrict__ Th, int sh,
                                  int Kd, int Nd) {
  __shared__ float tile[64][65];
  const int k0 = blockIdx.x * 64, n0 = blockIdx.y * 64;
  const int tx = threadIdx.x & 63, ty = threadIdx.x >> 6;
#pragma unroll
  for (int i = 0; i < 16; ++i)
    tile[ty * 16 + i][tx] = W[(size_t)(k0 + ty * 16 + i) * Nd + n0 + tx];
  __syncthreads();
#pragma unroll
  for (int i = 0; i < 16; ++i) {
    const int nn = ty * 16 + i;
    Th[(size_t)(n0 + nn) * sh + k0 + tx] = f2h(tile[tx][nn]);
  }
}

// ------- 128xBN fp16 MFMA GEMM, 16x16x32 fragments, BK=32 -------
// 8 waves (2m x 4n), wave tile 64x(BN/4). LDS: 3 slice buffers (BN=256: 72KB).
// r13-proven depth-2 counted pipeline: prologue stages tiles 0,1; iter tt
// issues STAGE(tt+2) (clamped: fixed load count); end-of-tile wait
// vmcnt(LOADS) — tile tt+1 landed, next stage's loads stay in flight.
// Cross-block overlap hides the barrier stall [r13/r15: 859 TF]. Row-pair 128B
// lines, phys granule = ((row&1)*4+kgran) ^ (line&7); conflicts = 0 (r7-r15).
// !FINAL: writes fp16 planes Ch (col>>10 selects plane; plane 4 -> C4h).
// FINAL: Cf = acc + xres + bias (fp32 out).
template <int FINAL, int BN>
__global__ __launch_bounds__(512, 2) void gemmT(
    const ushort* __restrict__ A, int lda, const ushort* __restrict__ Bw,
    ushort* __restrict__ Ch, ushort* __restrict__ C4h,
    float* __restrict__ Cf, const float* __restrict__ xres, const float* __restrict__ bias,
    int M, int K) {
  constexpr int SLICE = 8192 + BN * 64;  // A 8KB + B BN*64B
  constexpr int JJ = BN / 64;            // B frags per wave (4 or 2)
  __shared__ __align__(16) char ldsc[3 * SLICE];
  const int bid = blockIdx.x;
  const int tm = bid & 63, tn = bid >> 6;
  const int ldb = K;
  const int NT = K >> 5;
  const int t = threadIdx.x, lane = t & 63, wid = t >> 6;
  const int wm = wid >> 2, wn = wid & 3;

  f32x4 acc[4][JJ];
#pragma unroll
  for (int i = 0; i < 4; ++i)
#pragma unroll
    for (int j = 0; j < JJ; ++j) acc[i][j] = (f32x4){0.f, 0.f, 0.f, 0.f};

  // ---- staging: linear LDS dest t*16; inverse-swizzled global source ----
  const int line1 = t >> 3;
  const int g8s = (t & 7) ^ (line1 & 7);
  const int rowS = line1 * 2 + (g8s >> 2);   // 0..127
  const int kgS = (g8s & 3) << 3;
  const ushort* srcA = A + (size_t)(tm * 128 + rowS) * lda + kgS;
  const ushort* srcB = Bw + (size_t)(tn * BN + rowS) * ldb + kgS;
  char* dstA = ldsc + (size_t)t * 16;
  char* dstB = ldsc + 8192 + (size_t)t * 16;

  auto STAGE = [&](int tile, int slot) {
    const int ts = (tile < NT) ? tile : NT - 1;  // clamp: fixed load count
    char* ba = dstA + slot * SLICE;
    char* bb = dstB + slot * SLICE;
    gload16(srcA + ts * 32, ba);
    gload16(srcB + ts * 32, bb);
    if (BN == 256) gload16(srcB + (size_t)128 * ldb + ts * 32, bb + 8192);
  };
#define WAIT_OLDEST()                                               \
  if (BN == 256) { asm volatile("s_waitcnt vmcnt(3)" ::: "memory"); } \
  else           { asm volatile("s_waitcnt vmcnt(2)" ::: "memory"); }

  // ---- fragment reads (16x16x32): row = f*16 + lane15, kgran = lane>>4 ----
  const int lane15 = lane & 15;
  const int hl = lane15 >> 1;
  const int swz = ((((lane15 & 1) << 2) + (lane >> 4)) ^ hl) << 4;
  const char* aB = ldsc + wm * 4096 + hl * 128 + swz;
  const char* bB = ldsc + 8192 + wn * ((BN / 4) * 64) + hl * 128 + swz;

  // prologue: 2 tiles staged; wait for tile 0 only
  STAGE(0, 0); STAGE(1, 1);
  WAIT_OLDEST();
  __builtin_amdgcn_sched_barrier(0);
  __builtin_amdgcn_s_barrier();

  int s_rd = 0, s_st = 2;
#pragma unroll 1
  for (int tt = 0; tt < NT; ++tt) {
    STAGE(tt + 2, s_st);  // in flight: tiles tt+1, tt+2
    const char* ab = aB + s_rd * SLICE;
    const char* bb = bB + s_rd * SLICE;
    f16x8 af[4], bf_[JJ];
#pragma unroll
    for (int f = 0; f < 4; ++f) af[f] = *(const f16x8*)(ab + f * 1024);
#pragma unroll
    for (int c = 0; c < JJ; ++c) bf_[c] = *(const f16x8*)(bb + c * 1024);
    asm volatile("s_waitcnt lgkmcnt(0)" ::: "memory");
    __builtin_amdgcn_sched_barrier(0);
    __builtin_amdgcn_s_setprio(1);
#pragma unroll
    for (int f = 0; f < 4; ++f)
#pragma unroll
      for (int c = 0; c < JJ; ++c)
        acc[f][c] = __builtin_amdgcn_mfma_f32_16x16x32_f16(af[f], bf_[c], acc[f][c], 0, 0, 0);
    __builtin_amdgcn_s_setprio(0);
    WAIT_OLDEST();  // tile tt+1 landed; next stage stays in flight
    __builtin_amdgcn_sched_barrier(0);
    __builtin_amdgcn_s_barrier();
    s_rd = (s_rd == 2) ? 0 : s_rd + 1;
    s_st = (s_st == 2) ? 0 : s_st + 1;
  }
#undef WAIT_OLDEST

  // epilogue. C/D layout: col=lane&15, row=(lane>>4)*4+reg  [m89-verified]
#pragma unroll
  for (int i = 0; i < 4; ++i) {
    const int row0 = tm * 128 + wm * 64 + i * 16 + ((lane >> 4) << 2);
#pragma unroll
    for (int jj = 0; jj < JJ; ++jj) {
      const int col = tn * BN + wn * (BN / 4) + jj * 16 + lane15;
      if (FINAL) {
#pragma unroll
        for (int r = 0; r < 4; ++r) {
          const size_t idx = (size_t)(row0 + r) * 1024 + col;
          Cf[idx] = acc[i][jj][r] + xres[idx] + bias[col];
        }
      } else {
        const int pl = col >> 10;
        ushort* base = (pl < 4) ? (Ch + (size_t)pl * (size_t)M * 1024) : C4h;
#pragma unroll
        for (int r = 0; r < 4; ++r)
          base[(size_t)(row0 + r) * 1024 + (col & 1023)] = f2h(acc[i][jj][r]);
      }
    }
  }
}

// ---------------- fused elementwise / scan passes (fp16 planes + fp16 x) ----------------
// r16: CCH=128/LCH=16 -> 2048 waves (2/SIMD) for latency hiding (was 1/SIMD).

__device__ __forceinline__ void load4h(const ushort* p, float* f) {
  ushort4 u = *(const ushort4*)p;
  f[0] = h2f(u.x); f[1] = h2f(u.y); f[2] = h2f(u.z); f[3] = h2f(u.w);
}

// P1+P2: gating/sigmoid transforms in place (fp16) + per-(b,chunk,d) fp32 sums
__global__ void prep_chunk_kernel(ushort* __restrict__ omega_go, const ushort* __restrict__ gate_lin,
                                  ushort* __restrict__ mag_io,
                                  const float* __restrict__ b_om, const float* __restrict__ b_gate,
                                  const float* __restrict__ b_mag, const float* __restrict__ isc,
                                  float* __restrict__ gsum, float* __restrict__ msum) {
  int tid = blockIdx.x * blockDim.x + threadIdx.x;
  if (tid >= B_ * CCH * (D_ / 4)) return;
  int d4 = tid & 255, c = (tid >> 8) & (CCH - 1), b = tid >> 15;
  int d = d4 * 4;
  size_t base = ((size_t)(b * S_) + c * LCH) * D_ + d;
  size_t cs = ((size_t)(b * CCH) + c) * D_ + d;
  float bo[4], bg[4], bm[4], is[4];
  *(float4*)bo = *(const float4*)(b_om + d);
  *(float4*)bg = *(const float4*)(b_gate + d);
  *(float4*)bm = *(const float4*)(b_mag + d);
  *(float4*)is = *(const float4*)(isc + d);
  float sg[4] = {0.f, 0.f, 0.f, 0.f}, sm[4] = {0.f, 0.f, 0.f, 0.f};
  for (int s = 0; s < LCH; ++s) {
    size_t i = base + (size_t)s * D_;
    float om[4], gl[4], mg[4];
    load4h(omega_go + i, om);
    load4h(gate_lin + i, gl);
    load4h(mag_io + i, mg);
    ushort wo[4], wm_[4];
#pragma unroll
    for (int j = 0; j < 4; ++j) {
      float g = 1.f / (1.f + __expf(-(gl[j] + bg[j])));
      float m5 = 5.f / (1.f + __expf(-(mg[j] + bm[j])));
      float go = g * ((om[j] + bo[j]) * fabsf(is[j]));
      sg[j] += go;
      sm[j] += m5;
      wo[j] = f2h(go);
      wm_[j] = f2h(m5);
    }
    *(ushort4*)(omega_go + i) = *(ushort4*)wo;
    *(ushort4*)(mag_io + i) = *(ushort4*)wm_;
  }
  *(float4*)(gsum + cs) = *(float4*)sg;
  *(float4*)(msum + cs) = *(float4*)sm;
}

// P3/P5: exclusive scan of 128 chunk totals per (b,d): two 64-lane passes + carry
__global__ void scan_offsets_kernel(float* __restrict__ s1, float* __restrict__ s2) {
  int gw = (blockIdx.x * blockDim.x + threadIdx.x) >> 6;
  int lane = threadIdx.x & 63;
  if (gw >= B_ * D_) return;
  int d = gw & (D_ - 1), b = gw >> 10;
  float c1 = 0.f, c2 = 0.f;
#pragma unroll
  for (int h = 0; h < 2; ++h) {
    size_t idx = ((size_t)(b * CCH) + h * 64 + lane) * D_ + d;
    float v1 = s1[idx], v2 = s2[idx];
#pragma unroll
    for (int off = 1; off < 64; off <<= 1) {
      float u1 = __shfl_up(v1, off);
      float u2 = __shfl_up(v2, off);
      if (lane >= off) { v1 += u1; v2 += u2; }
    }
    float e1 = __shfl_up(v1, 1), e2 = __shfl_up(v2, 1);
    if (lane == 0) { e1 = 0.f; e2 = 0.f; }
    s1[idx] = e1 + c1;
    s2[idx] = e2 + c2;
    c1 += __shfl(v1, 63);
    c2 += __shfl(v2, 63);
  }
}

// P4 (slim): chunked scan -> ctx parts 0,1 + tr/ti chunk totals. Planes untouched.
__global__ void phase_scan_kernel(const ushort* __restrict__ xh, const ushort* __restrict__ go,
                                  const ushort* __restrict__ mag, const ushort* __restrict__ p0,
                                  const float* __restrict__ goff,
                                  float* __restrict__ trsum, float* __restrict__ tisum,
                                  const float* __restrict__ b_phi, ushort* __restrict__ ctx) {
  int tid = blockIdx.x * blockDim.x + threadIdx.x;
  if (tid >= B_ * CCH * (D_ / 4)) return;
  int d4 = tid & 255, c = (tid >> 8) & (CCH - 1), b = tid >> 15;
  int d = d4 * 4;
  size_t base = ((size_t)(b * S_) + c * LCH) * D_ + d;
  size_t cs = ((size_t)(b * CCH) + c) * D_ + d;
  float pr[4], bp[4];
  *(float4*)pr = *(const float4*)(goff + cs);
  *(float4*)bp = *(const float4*)(b_phi + d);
  float tr[4] = {0.f, 0.f, 0.f, 0.f}, ti[4] = {0.f, 0.f, 0.f, 0.f};
  size_t crow = ((size_t)(b * S_ + c * LCH)) * 4096 + d;
  for (int s = 0; s < LCH; ++s) {
    size_t i = base + (size_t)s * D_;
    float g[4], ph0[4], m[4], xv[4];
    load4h(go + i, g);
    load4h(p0 + i, ph0);
    load4h(mag + i, m);
    load4h(xh + i, xv);
    ushort c4[4], s4[4];
#pragma unroll
    for (int j = 0; j < 4; ++j) {
      pr[j] += g[j];
      float ph = ph0[j] + bp[j] + pr[j];
      float sp, cp;
      __sincosf(ph, &sp, &cp);
      float wr = m[j] * xv[j];
      tr[j] += wr * cp;
      ti[j] += wr * sp;
      c4[j] = f2h(xv[j] * cp);
      s4[j] = f2h(xv[j] * sp);
    }
    *(ushort4*)(ctx + crow) = *(ushort4*)c4;
    *(ushort4*)(ctx + crow + 1024) = *(ushort4*)s4;
    crow += 4096;
  }
  *(float4*)(trsum + cs) = *(float4*)tr;
  *(float4*)(tisum + cs) = *(float4*)ti;
}

// P6 (recompute): re-run the chunk chains, normalize + retrieve -> ctx parts 2,3
__global__ void retrieve_kernel(const ushort* __restrict__ xh, const ushort* __restrict__ go,
                                const ushort* __restrict__ mag, const ushort* __restrict__ p0,
                                const ushort* __restrict__ q,
                                const float* __restrict__ goff, const float* __restrict__ moff,
                                const float* __restrict__ troff, const float* __restrict__ tioff,
                                const float* __restrict__ b_phi, const float* __restrict__ b_q,
                                ushort* __restrict__ ctx) {
  int tid = blockIdx.x * blockDim.x + threadIdx.x;
  if (tid >= B_ * CCH * (D_ / 4)) return;
  int d4 = tid & 255, c = (tid >> 8) & (CCH - 1), b = tid >> 15;
  int d = d4 * 4;
  size_t base = ((size_t)(b * S_) + c * LCH) * D_ + d;
  size_t cs = ((size_t)(b * CCH) + c) * D_ + d;
  float pr[4], mr[4], tr[4], ti[4], bp[4], bq[4];
  *(float4*)pr = *(const float4*)(goff + cs);
  *(float4*)mr = *(const float4*)(moff + cs);
  *(float4*)tr = *(const float4*)(troff + cs);
  *(float4*)ti = *(const float4*)(tioff + cs);
  *(float4*)bp = *(const float4*)(b_phi + d);
  *(float4*)bq = *(const float4*)(b_q + d);
  size_t crow = ((size_t)(b * S_ + c * LCH)) * 4096 + d;
  for (int s = 0; s < LCH; ++s) {
    size_t i = base + (size_t)s * D_;
    float g[4], ph0[4], m[4], xv[4], qv[4];
    load4h(go + i, g);
    load4h(p0 + i, ph0);
    load4h(mag + i, m);
    load4h(q + i, qv);
    load4h(xh + i, xv);
    ushort r2[4], r3[4];
#pragma unroll
    for (int j = 0; j < 4; ++j) {
      pr[j] += g[j];
      float ph = ph0[j] + bp[j] + pr[j];
      float sp, cp;
      __sincosf(ph, &sp, &cp);
      mr[j] += m[j];
      float wr = m[j] * xv[j];
      tr[j] += wr * cp;
      ti[j] += wr * sp;
      float rs = rsqrtf(mr[j] + 1e-8f);
      float mreal = tr[j] * rs, mimag = ti[j] * rs;
      float phq = ph + qv[j] + bq[j];
      float sq, cq;
      __sincosf(phq, &sq, &cq);
      r2[j] = f2h(mreal * cq + mimag * sq);
      r3[j] = f2h(mimag * cq - mreal * sq);
    }
    *(ushort4*)(ctx + crow + 2048) = *(ushort4*)r2;
    *(ushort4*)(ctx + crow + 3072) = *(ushort4*)r3;
    crow += 4096;
  }
}

// ---------------- launcher ----------------
extern "C" void kernel_launch(void* const* d_in, const int* in_sizes, int n_in,
                              void* d_out, int out_size, void* d_ws, size_t ws_size,
                              hipStream_t stream) {
  const float* x      = (const float*)d_in[0];
  const float* W_om   = (const float*)d_in[1];
  const float* b_om   = (const float*)d_in[2];
  const float* W_mag  = (const float*)d_in[3];
  const float* b_mag  = (const float*)d_in[4];
  const float* W_phi  = (const float*)d_in[5];
  const float* b_phi  = (const float*)d_in[6];
  const float* W_gate = (const float*)d_in[7];
  const float* b_gate = (const float*)d_in[8];
  const float* W_q    = (const float*)d_in[9];
  const float* b_q    = (const float*)d_in[10];
  const float* isc    = (const float*)d_in[11];
  const float* W_out  = (const float*)d_in[12];
  const float* b_out  = (const float*)d_in[13];
  float* out = (float*)d_out;

  // ---- ws layout, 213,909,504 bytes ----
  // [0, 67108864)          4 fp16 planes: omega|gate|mag|phi0
  // [67108864, 83886080)   x_h fp16 [8192][1024] (lives through retrieve)
  // [83886080, 92274688)   gsum|msum|trsum|tisum (4 x 2MB, CCH=128)
  // [134217728, 201326592) ctx fp16 [8192][4096]; W5T (10.5MB, dead after GEMM1)
  //                        overlapped at +16777216
  // [201326592)            WoutT [1024][4096] fp16
  // q_lin (fp16) lives in d_out (overwritten by the final GEMM afterwards).
  const size_t WS_NEEDED = 213909504ull;
  if (ws_size < WS_NEEDED) {
    (void)hipMemsetAsync(d_out, 0, (size_t)out_size * sizeof(float), stream);
    return;
  }
  char* w = (char*)d_ws;
  ushort* planes_h = (ushort*)w;                      // 4 x NELEM fp16
  ushort* omega_buf = planes_h;
  ushort* gate_buf  = planes_h + NELEM;
  ushort* mag_buf   = planes_h + 2 * NELEM;
  ushort* phi0_buf  = planes_h + 3 * NELEM;
  ushort* x_h   = (ushort*)(w + 67108864);            // [8192][1024] fp16
  ushort* q_buf = (ushort*)out;                       // fp16 q plane in d_out
  float* gsum  = (float*)(w + 83886080);
  float* msum  = (float*)(w + 85983232);
  float* trsum = (float*)(w + 88080384);
  float* tisum = (float*)(w + 90177536);
  char* ctxb = w + 4 * NELEM * 4;
  ushort* ctx   = (ushort*)ctxb;
  ushort* W5T   = (ushort*)(ctxb + 16777216);         // [5120][1024]: om|gate|mag|phi0|q
  ushort* WoutT = (ushort*)(w + 201326592);           // [1024][4096]

  // conversions (batched)
  xhalf_kernel<<<(int)(NELEM / 2048), 256, 0, stream>>>(x, x_h);
  transpose5<<<dim3(16, 16, 5), 256, 0, stream>>>(W_om, W_gate, W_mag, W_phi, W_q, W5T);
  transpose_convert<<<dim3(64, 16), 256, 0, stream>>>(W_out, WoutT, 4096, 4 * D_, D_);

  // GEMM1: 5 projections, N=5120, K=1024. 1280 blocks (5 exact rounds),
  // 72KB LDS -> 2 blocks/CU resident (r13/r15 config: 859 TF).
  gemmT<0, 256><<<1280, 512, 0, stream>>>(x_h, 1024, W5T, planes_h, q_buf,
                                          nullptr, nullptr, nullptr, MROWS, 1024);

  // scans + fused elementwise (CCH=128: 2 waves/SIMD)
  prep_chunk_kernel<<<B_ * CCH * (D_ / 4) / 256, 256, 0, stream>>>(
      omega_buf, gate_buf, mag_buf, b_om, b_gate, b_mag, isc, gsum, msum);
  scan_offsets_kernel<<<B_ * D_ * 64 / 256, 256, 0, stream>>>(gsum, msum);
  phase_scan_kernel<<<B_ * CCH * (D_ / 4) / 256, 256, 0, stream>>>(
      x_h, omega_buf, mag_buf, phi0_buf, gsum, trsum, tisum, b_phi, ctx);
  scan_offsets_kernel<<<B_ * D_ * 64 / 256, 256, 0, stream>>>(trsum, tisum);
  retrieve_kernel<<<B_ * CCH * (D_ / 4) / 256, 256, 0, stream>>>(
      x_h, omega_buf, mag_buf, phi0_buf, q_buf, gsum, msum, trsum, tisum, b_phi, b_q, ctx);

  // final: out = x + ctx @ W_out + b_out. r13-proven config: BN=256,
  // 256 blocks, 72KB LDS, counted pipeline.
  gemmT<1, 256><<<256, 512, 0, stream>>>(ctx, 4096, WoutT, nullptr, nullptr, out,
                                         x, b_out, MROWS, 4 * D_);
}